// Round 3
// baseline (323.067 us; speedup 1.0000x reference)
//
#include <hip/hip_runtime.h>
#include <stdint.h>

#define D_DIM 256
#define BI 64        // i-rows per block (2 blocks/CU)
#define TJ 128       // j-tile
#define CHUNK 4096   // j per block (grid = 128 x 4 = 512 blocks = 2/CU)

typedef unsigned short ushort_t;
typedef __attribute__((ext_vector_type(8))) short bf16x8;   // 8 bf16 = 4 VGPRs
typedef __attribute__((ext_vector_type(4))) float f32x4;

__device__ __forceinline__ unsigned short f2bf(float f) {
  union { float f; unsigned u; } x; x.f = f;
  unsigned r = x.u + 0x7FFFu + ((x.u >> 16) & 1u);  // round-nearest-even
  return (unsigned short)(r >> 16);
}

__device__ __forceinline__ float fast_sqrt(float x) {
#if __has_builtin(__builtin_amdgcn_sqrtf)
  return __builtin_amdgcn_sqrtf(x);
#else
  return sqrtf(x);
#endif
}
__device__ __forceinline__ float fast_exp2(float x) {
#if __has_builtin(__builtin_amdgcn_exp2f)
  return __builtin_amdgcn_exp2f(x);
#else
  return exp2f(x);
#endif
}

// async global->LDS, 16B per lane. LDS dest = wave-uniform base + lane*16.
__device__ __forceinline__ void g2l16(const void* g, void* l) {
  __builtin_amdgcn_global_load_lds(
      (__attribute__((address_space(1))) void*)(uintptr_t)g,
      (__attribute__((address_space(3))) void*)(unsigned)(uintptr_t)l,
      16, 0, 0);
}

// ---------------- prep: cast + row norms + A-fragment layout, fused ----------------
__global__ __launch_bounds__(256) void
prep_AB(const float* __restrict__ G, const float* __restrict__ P,
        ushort_t* __restrict__ Tb, ushort_t* __restrict__ TbF,
        float* __restrict__ nrm, int Bn)
{
  __shared__ ushort_t Ls[16 * 256];
  const int b = blockIdx.x, t = threadIdx.x;
  const int r0 = b * 16, lane = t & 63;
  #pragma unroll
  for (int it = 0; it < 16; it++) {
    const int r = r0 + it;
    const float* src = (r < Bn) ? (G + (size_t)r * D_DIM)
                                : (P + (size_t)(r - Bn) * D_DIM);
    float v = src[t];
    ushort_t u = f2bf(v);
    Tb[(size_t)r * D_DIM + t] = u;
    Ls[it * 256 + t] = u;
    float s = v * v;
    #pragma unroll
    for (int o = 32; o > 0; o >>= 1) s += __shfl_down(s, o, 64);
    if (lane == 0) atomicAdd(&nrm[r], s);
  }
  __syncthreads();
  #pragma unroll
  for (int it = 0; it < 16; it++) {
    int flat = it * 256 + t;                   // [0, 4096)
    int ks = flat >> 9, e = flat & 511;
    int q = e >> 7, m = (e >> 3) & 15, idx = e & 7;
    TbF[(size_t)b * 4096 + flat] = Ls[m * 256 + ks * 32 + q * 8 + idx];
  }
}

// ---- prep: Tb -> TTF (transposed, fragment-linear): block(dgrp16, jstep32)
__global__ __launch_bounds__(256) void
prep_fragT(const ushort_t* __restrict__ Tb, ushort_t* __restrict__ TTF, int Ttot)
{
  __shared__ ushort_t Ts[64][72];
  const int t = threadIdx.x;
  const int j0 = blockIdx.x * 64, d0 = blockIdx.y * 64;
  #pragma unroll
  for (int qq = 0; qq < 16; qq++) {
    int idx = qq * 256 + t;
    int jr = idx >> 6, dc = idx & 63;
    Ts[dc][jr] = Tb[(size_t)(j0 + jr) * D_DIM + d0 + dc];
  }
  __syncthreads();
  #pragma unroll
  for (int it = 0; it < 16; it++) {
    int flat = it * 256 + t;                   // [0, 4096)
    int blk = flat >> 9, e = flat & 511;
    int jsub = blk & 1, dsub = blk >> 1;       // 2 j-steps x 4 d-grps
    int q = e >> 7, m = (e >> 3) & 15, idx = e & 7;
    ushort_t val = Ts[dsub * 16 + m][jsub * 32 + q * 8 + idx];
    const int dgrp = (d0 >> 4) + dsub;
    const int jstep = (j0 >> 5) + jsub;
    TTF[((size_t)dgrp * (Ttot >> 5) + jstep) * 512 + e] = val;
  }
}

// ---------------- fused: S^T -> kv (LDS dbuf) -> O^T, 1 barrier/tile ----------------
// Round-10: LDS-pressure rebalance. Round-2's grids duplicated LDS reads
// (bf x4, kf x8 -> 544 KB/CU-tile at the 85 B/cyc b128 ceiling = the real
// co-limiter; MfmaUtil 38% was the consequence). New wave grids:
//   GEMM1: 2(j64) x 4(i16) per wave -> bf dup x2 (was x4); af dup x4 (L2,
//          same-address lockstep readers -> L1/L2 merge).
//   GEMM2: 4(d64) x 2(i32) per wave -> kf dup x4 (was x8); a2 dup x2.
// LDS per CU-tile: 544 -> 288 KB, below the 4966-cyc MFMA demand.
// Plus: raw s_barrier with lgkmcnt-only drain (af/a2 prefetches stay in
// flight across the barrier, T4-lite) and setprio around MFMA clusters.
__global__ __launch_bounds__(512, 4) void
fused_kernel(const ushort_t* __restrict__ Tb, const ushort_t* __restrict__ TbF,
             const ushort_t* __restrict__ TTF, const float* __restrict__ nrm,
             float* __restrict__ sg, float* __restrict__ sp,
             float* __restrict__ Part, int Bn, int Ttot)
{
  __shared__ ushort_t Gsm[4 * 4096];      // 32 KB resident i-tile: [kq][row64][64 ^ swz]
  __shared__ ushort_t Ksm[2][64 * 128];   // 2 x 16 KB kv: [i64][128j ^ swz]

  const int t = threadIdx.x;
  const int w = t >> 6, lane = t & 63;
  const int q = lane >> 4, c = lane & 15;
  const int jg = w >> 2, ig = w & 3;      // GEMM1 grid: 2(j64) x 4(i16)
  const int dg = w & 3, ig2 = w >> 2;     // GEMM2 grid: 4(d64) x 2(i32)
  const int i0 = blockIdx.x * BI;
  const int chunk0 = blockIdx.y * CHUNK;
  const bool gen = (chunk0 < Bn);
  const int swz = (c & 7) * 8;            // per-lane constant XOR
  const int jsteps = Ttot >> 5;
  const size_t mstride = (size_t)jsteps * 512;

  // ---- stage resident G tile (64 rows x 256 k, swizzled) ----
  const int srow = t >> 3;                               // 0..63
  const int scol = ((t & 7) * 8) ^ ((srow & 7) * 8);     // source col within 64
  {
    const ushort_t* gsrc = Tb + (size_t)(i0 + srow) * D_DIM;
    #pragma unroll
    for (int kq = 0; kq < 4; kq++)
      g2l16(gsrc + kq * 64 + scol, Gsm + kq * 4096 + t * 8);
  }

  f32x4 accO[4][2];
  #pragma unroll
  for (int m = 0; m < 4; m++)
    #pragma unroll
    for (int n = 0; n < 2; n++) accO[m][n] = (f32x4)0.f;
  float rs = 0.f;
  const float ni = nrm[i0 + ig * 16 + c];
  const int ig_glob = i0 + ig * 16 + c;

  // persistent GEMM1 af prefetch registers (ks=0 of current tile, 4 jm streams)
  bf16x8 afc[4];
  {
    const ushort_t* ap = TbF + ((size_t)((chunk0 >> 4) + jg * 4) * 8) * 512 + lane * 8;
    #pragma unroll
    for (int jm = 0; jm < 4; jm++) afc[jm] = *(const bf16x8*)(ap + jm * 4096);
  }

  __syncthreads();   // Gsm ready (full drain incl. global_load_lds)

  for (int jt = 0; jt < CHUNK; jt += TJ) {
    const int j0g = chunk0 + jt;
    ushort_t* Kbuf = Ksm[(jt >> 7) & 1];
    const ushort_t* afp = TbF + ((size_t)((j0g >> 4) + jg * 4) * 8) * 512 + lane * 8;

    // prefetch nrm[j] for this tile's epilogue (hidden under GEMM1)
    float4 njv[4];
    #pragma unroll
    for (int jm = 0; jm < 4; jm++)
      njv[jm] = *(const float4*)&nrm[j0g + jg * 64 + jm * 16 + q * 4];

    // ---- GEMM1: S^T[j64 x i16] per wave, K=256; af global (dbuf), bf from Gsm ----
    f32x4 acc1[4];
    #pragma unroll
    for (int jm = 0; jm < 4; jm++) acc1[jm] = (f32x4)0.f;

    #pragma unroll
    for (int ks = 0; ks < 8; ks++) {
      bf16x8 afn[4];
      if (ks < 7) {
        #pragma unroll
        for (int jm = 0; jm < 4; jm++)
          afn[jm] = *(const bf16x8*)(afp + jm * 4096 + (ks + 1) * 512);
      }
      bf16x8 bfv = *(const bf16x8*)&Gsm[(ks >> 1) * 4096 + (ig * 16 + c) * 64 + ((((ks & 1) * 32) + q * 8) ^ swz)];
      __builtin_amdgcn_s_setprio(1);
      #pragma unroll
      for (int jm = 0; jm < 4; jm++)
        acc1[jm] = __builtin_amdgcn_mfma_f32_16x16x32_bf16(afc[jm], bfv, acc1[jm], 0, 0, 0);
      __builtin_amdgcn_s_setprio(0);
      if (ks < 7) {
        #pragma unroll
        for (int jm = 0; jm < 4; jm++) afc[jm] = afn[jm];
      }
    }

    // cross-tile af prefetch (ks=0 of next tile): in flight through
    // epilogue + raw barrier + GEMM2 (barrier no longer drains vmcnt)
    {
      const int jn = (jt + TJ < CHUNK) ? (j0g + TJ) : chunk0;
      const ushort_t* ap = TbF + ((size_t)((jn >> 4) + jg * 4) * 8) * 512 + lane * 8;
      #pragma unroll
      for (int jm = 0; jm < 4; jm++) afc[jm] = *(const bf16x8*)(ap + jm * 4096);
    }

    // this tile's a2 ks=0 prefetch (4 d-streams): L2 latency hides under epilogue
    const ushort_t* a2p = TTF + ((size_t)(dg * 4) * jsteps + (j0g >> 5)) * 512 + lane * 8;
    bf16x8 a2c[4];
    #pragma unroll
    for (int m = 0; m < 4; m++) a2c[m] = *(const bf16x8*)(a2p + m * mstride);

    // ---- epilogue: kv = exp(-dist/20), rowsums, pack -> Kbuf ----
    #pragma unroll
    for (int jm = 0; jm < 4; jm++) {
      const int jl = jg * 64 + jm * 16 + q * 4;   // local j of reg 0
      const int jb = j0g + jl;                    // global j
      const float nj[4] = {njv[jm].x, njv[jm].y, njv[jm].z, njv[jm].w};
      uint32_t pb[4];
      #pragma unroll
      for (int reg = 0; reg < 4; reg++) {
        float sq = fmaxf(ni + nj[reg] - 2.f * acc1[jm][reg], 0.f);
        float dd = fast_sqrt(sq);
        float kv = fast_exp2(dd * -0.07213475204444817f);  // exp(-dd/20)
        if (gen && (jb + reg == ig_glob)) kv = 0.f;
        rs += kv;
        union { float f; uint32_t u; } uu; uu.f = kv; pb[reg] = uu.u;
      }
      uint2 pk;  // truncating bf16 pack
      pk.x = __builtin_amdgcn_perm(pb[1], pb[0], 0x07060302u);
      pk.y = __builtin_amdgcn_perm(pb[3], pb[2], 0x07060302u);
      *(uint2*)&Kbuf[(ig * 16 + c) * 128 + (jl ^ swz)] = pk;
    }

    // tile barrier: drain LDS writes only; vmem prefetches stay in flight (T4-lite)
    asm volatile("s_waitcnt lgkmcnt(0)" ::: "memory");
    __builtin_amdgcn_s_barrier();
    __builtin_amdgcn_sched_barrier(0);

    // ---- GEMM2: O^T[d64 x i32] per wave, K=128; a2 global (dbuf), kf from Kbuf ----
    #pragma unroll
    for (int ks = 0; ks < 4; ks++) {
      bf16x8 a2n[4];
      if (ks < 3) {
        #pragma unroll
        for (int m = 0; m < 4; m++)
          a2n[m] = *(const bf16x8*)(a2p + m * mstride + (ks + 1) * 512);
      }
      bf16x8 kfv[2];
      #pragma unroll
      for (int nt = 0; nt < 2; nt++)
        kfv[nt] = *(const bf16x8*)&Kbuf[(ig2 * 32 + nt * 16 + c) * 128 + ((ks * 32 + q * 8) ^ swz)];
      __builtin_amdgcn_s_setprio(1);
      #pragma unroll
      for (int m = 0; m < 4; m++)
        #pragma unroll
        for (int nt = 0; nt < 2; nt++)
          accO[m][nt] = __builtin_amdgcn_mfma_f32_16x16x32_bf16(a2c[m], kfv[nt], accO[m][nt], 0, 0, 0);
      __builtin_amdgcn_s_setprio(0);
      if (ks < 3) {
        #pragma unroll
        for (int m = 0; m < 4; m++) a2c[m] = a2n[m];
      }
    }
    // no barrier: next tile writes the other Ksm buffer
  }

  // rowsum partials -> sg/sp
  float* S = gen ? sg : sp;
  {
    float r = rs;
    r += __shfl_xor(r, 16, 64);
    r += __shfl_xor(r, 32, 64);
    if (lane < 16) atomicAdd(&S[i0 + ig * 16 + lane], r);
  }
  // O^T partials -> Part[chunk][i][d] (f32x4, 16B aligned)
  float* Pdst = Part + (size_t)blockIdx.y * ((size_t)8192 * D_DIM);
  #pragma unroll
  for (int m = 0; m < 4; m++)
    #pragma unroll
    for (int nt = 0; nt < 2; nt++) {
      const int d = dg * 64 + m * 16 + q * 4;
      const int igr = i0 + ig2 * 32 + nt * 16 + c;
      *(f32x4*)&Pdst[(size_t)igr * D_DIM + d] = accO[m][nt];
    }
}

// ---------------- combine: out = sg*sum(pos parts) - sp*sum(gen parts) ----------------
__global__ __launch_bounds__(256) void
combine_kernel(float* __restrict__ out, const float* __restrict__ Part,
               const float* __restrict__ sg, const float* __restrict__ sp)
{
  const size_t idx = (size_t)blockIdx.x * 256 + threadIdx.x;   // f32x4 index
  const size_t qstride = (size_t)8192 * (D_DIM / 4);
  const int i = (int)(idx >> 6);
  const f32x4* p = (const f32x4*)Part;
  f32x4 g0 = p[idx], g1 = p[idx + qstride];
  f32x4 p0 = p[idx + 2 * qstride], p1 = p[idx + 3 * qstride];
  const float sgv = sg[i], spv = sp[i];
  f32x4 r;
  #pragma unroll
  for (int k = 0; k < 4; k++) r[k] = sgv * (p0[k] + p1[k]) - spv * (g0[k] + g1[k]);
  ((f32x4*)out)[idx] = r;
}

extern "C" void kernel_launch(void* const* d_in, const int* in_sizes, int n_in,
                              void* d_out, int out_size, void* d_ws, size_t ws_size,
                              hipStream_t stream)
{
  const float* G = (const float*)d_in[0];
  const float* P = (const float*)d_in[1];
  const int Bn = in_sizes[0] / D_DIM;   // 8192
  const int Xn = in_sizes[1] / D_DIM;   // 8192
  const int Ttot = Bn + Xn;             // 16384

  // workspace (~56.4 MiB)
  uint8_t* ws = (uint8_t*)d_ws;
  size_t off = 0;
  ushort_t* Tb  = (ushort_t*)(ws + off); off += (size_t)Ttot * D_DIM * 2;  // 8 MiB
  ushort_t* TbF = (ushort_t*)(ws + off); off += (size_t)Ttot * D_DIM * 2;  // 8 MiB
  ushort_t* TTF = (ushort_t*)(ws + off); off += (size_t)Ttot * D_DIM * 2;  // 8 MiB
  float* nrm = (float*)(ws + off); off += (size_t)Ttot * 4;
  float* sg  = (float*)(ws + off); off += (size_t)Bn * 4;
  float* sp  = (float*)(ws + off); off += (size_t)Bn * 4;
  off = (off + 255) & ~(size_t)255;
  float* Part = (float*)(ws + off); off += (size_t)4 * Bn * D_DIM * 4;     // 32 MiB
  if (ws_size < off) return;  // clean-fail signature if ws too small

  // zero nrm + sg + sp (contiguous)
  hipMemsetAsync(nrm, 0, ((size_t)Ttot + 2 * (size_t)Bn) * sizeof(float), stream);

  prep_AB<<<Ttot / 16, 256, 0, stream>>>(G, P, Tb, TbF, nrm, Bn);
  prep_fragT<<<dim3(Ttot / 64, D_DIM / 64), 256, 0, stream>>>(Tb, TTF, Ttot);
  fused_kernel<<<dim3(Bn / BI, Ttot / CHUNK), 512, 0, stream>>>(
      Tb, TbF, TTF, nrm, sg, sp, Part, Bn, Ttot);
  combine_kernel<<<(Bn * D_DIM / 4) / 256, 256, 0, stream>>>((float*)d_out, Part, sg, sp);
}

// Round 4
// 228.986 us; speedup vs baseline: 1.4109x; 1.4109x over previous
//
#include <hip/hip_runtime.h>
#include <stdint.h>

#define D_DIM 256
#define BI 64        // i-rows per block (2 blocks/CU)
#define TJ 128       // j-tile
#define CHUNK 4096   // j per block (grid = 128 x 4 = 512 blocks = 2/CU)

typedef unsigned short ushort_t;
typedef __attribute__((ext_vector_type(8))) short bf16x8;   // 8 bf16 = 4 VGPRs
typedef __attribute__((ext_vector_type(4))) float f32x4;

__device__ __forceinline__ unsigned short f2bf(float f) {
  union { float f; unsigned u; } x; x.f = f;
  unsigned r = x.u + 0x7FFFu + ((x.u >> 16) & 1u);  // round-nearest-even
  return (unsigned short)(r >> 16);
}

__device__ __forceinline__ float fast_sqrt(float x) {
#if __has_builtin(__builtin_amdgcn_sqrtf)
  return __builtin_amdgcn_sqrtf(x);
#else
  return sqrtf(x);
#endif
}
__device__ __forceinline__ float fast_exp2(float x) {
#if __has_builtin(__builtin_amdgcn_exp2f)
  return __builtin_amdgcn_exp2f(x);
#else
  return exp2f(x);
#endif
}

// async global->LDS, 16B per lane. LDS dest = wave-uniform base + lane*16.
__device__ __forceinline__ void g2l16(const void* g, void* l) {
  __builtin_amdgcn_global_load_lds(
      (__attribute__((address_space(1))) void*)(uintptr_t)g,
      (__attribute__((address_space(3))) void*)(unsigned)(uintptr_t)l,
      16, 0, 0);
}

// ---------------- prep: cast + row norms + A-fragment layout, fused ----------------
__global__ __launch_bounds__(256) void
prep_AB(const float* __restrict__ G, const float* __restrict__ P,
        ushort_t* __restrict__ Tb, ushort_t* __restrict__ TbF,
        float* __restrict__ nrm, int Bn)
{
  __shared__ ushort_t Ls[16 * 256];
  const int b = blockIdx.x, t = threadIdx.x;
  const int r0 = b * 16, lane = t & 63;
  #pragma unroll
  for (int it = 0; it < 16; it++) {
    const int r = r0 + it;
    const float* src = (r < Bn) ? (G + (size_t)r * D_DIM)
                                : (P + (size_t)(r - Bn) * D_DIM);
    float v = src[t];
    ushort_t u = f2bf(v);
    Tb[(size_t)r * D_DIM + t] = u;
    Ls[it * 256 + t] = u;
    float s = v * v;
    #pragma unroll
    for (int o = 32; o > 0; o >>= 1) s += __shfl_down(s, o, 64);
    if (lane == 0) atomicAdd(&nrm[r], s);
  }
  __syncthreads();
  #pragma unroll
  for (int it = 0; it < 16; it++) {
    int flat = it * 256 + t;                   // [0, 4096)
    int ks = flat >> 9, e = flat & 511;
    int q = e >> 7, m = (e >> 3) & 15, idx = e & 7;
    TbF[(size_t)b * 4096 + flat] = Ls[m * 256 + ks * 32 + q * 8 + idx];
  }
}

// ---- prep: Tb -> TTF (transposed, fragment-linear): block(dgrp16, jstep32)
__global__ __launch_bounds__(256) void
prep_fragT(const ushort_t* __restrict__ Tb, ushort_t* __restrict__ TTF, int Ttot)
{
  __shared__ ushort_t Ts[64][72];
  const int t = threadIdx.x;
  const int j0 = blockIdx.x * 64, d0 = blockIdx.y * 64;
  #pragma unroll
  for (int qq = 0; qq < 16; qq++) {
    int idx = qq * 256 + t;
    int jr = idx >> 6, dc = idx & 63;
    Ts[dc][jr] = Tb[(size_t)(j0 + jr) * D_DIM + d0 + dc];
  }
  __syncthreads();
  #pragma unroll
  for (int it = 0; it < 16; it++) {
    int flat = it * 256 + t;                   // [0, 4096)
    int blk = flat >> 9, e = flat & 511;
    int jsub = blk & 1, dsub = blk >> 1;       // 2 j-steps x 4 d-grps
    int q = e >> 7, m = (e >> 3) & 15, idx = e & 7;
    ushort_t val = Ts[dsub * 16 + m][jsub * 32 + q * 8 + idx];
    const int dgrp = (d0 >> 4) + dsub;
    const int jstep = (j0 >> 5) + jsub;
    TTF[((size_t)dgrp * (Ttot >> 5) + jstep) * 512 + e] = val;
  }
}

// ---------------- fused: S^T -> kv (LDS dbuf) -> O^T, 1 barrier/tile ----------------
// Round-12: round-2 structure (proven 162 us) + two bubble cuts:
//  (a) XCD-chunk swizzle: blocks remapped so each XCD (bid%8 round-robin,
//      m09) serves ONE chunk-half -> per-XCD L2 working set ~4 MB (TbF chunk
//      2 MB + TTF j-slice 2 MB) instead of 16 MB -> af/a2 fragment streams
//      become L2 hits (latency ~200 vs ~450+ cyc).
//  (b) a2-ks0 + next-tile-af loads hoisted BEFORE __syncthreads: the
//      compiler's forced vmcnt(0) drain at the barrier becomes a prefetch
//      completion point; loads issue under the epilogue VALU work, so GEMM2
//      starts with operands in registers (was: all 8 waves stall together on
//      a2-ks0 right after the barrier, a whole-CU bubble every tile).
__global__ __launch_bounds__(512, 4) void
fused_kernel(const ushort_t* __restrict__ Tb, const ushort_t* __restrict__ TbF,
             const ushort_t* __restrict__ TTF, const float* __restrict__ nrm,
             float* __restrict__ sg, float* __restrict__ sp,
             float* __restrict__ Part, int Bn, int Ttot)
{
  __shared__ ushort_t Gsm[4 * 4096];      // 32 KB resident i-tile: [kq][row64][64 ^ swz]
  __shared__ ushort_t Ksm[2][64 * 128];   // 2 x 16 KB kv: [i64][128j ^ swz]

  const int t = threadIdx.x;
  const int w = t >> 6, lane = t & 63;
  const int q = lane >> 4, c = lane & 15;
  const int wj = w >> 1, wcol = w & 1;    // GEMM1 4x2 wave grid (32j x 32i each)
  const int wd = w;                       // GEMM2 8x1 wave grid (32d x 64i each)

  // XCD-chunk swizzle (bijective): XCD k <- chunk k>>1; i-blocks interleave.
  const int bid = blockIdx.y * gridDim.x + blockIdx.x;
  const int by = (bid & 7) >> 1;                  // chunk index 0..3
  const int bx = ((bid >> 3) << 1) | (bid & 1);   // i-block 0..127
  const int i0 = bx * BI;
  const int chunk0 = by * CHUNK;
  const bool gen = (chunk0 < Bn);
  const int swz = (c & 7) * 8;            // per-lane constant XOR
  const int jsteps = Ttot >> 5;
  const size_t mstride = (size_t)jsteps * 512;

  // ---- stage resident G tile (64 rows x 256 k, swizzled) ----
  const int srow = t >> 3;                               // 0..63
  const int scol = ((t & 7) * 8) ^ ((srow & 7) * 8);     // source col within 64
  {
    const ushort_t* gsrc = Tb + (size_t)(i0 + srow) * D_DIM;
    #pragma unroll
    for (int kq = 0; kq < 4; kq++)
      g2l16(gsrc + kq * 64 + scol, Gsm + kq * 4096 + t * 8);
  }

  f32x4 accO[2][4];
  #pragma unroll
  for (int m = 0; m < 2; m++)
    #pragma unroll
    for (int n = 0; n < 4; n++) accO[m][n] = (f32x4)0.f;
  float rs[2] = {0.f, 0.f};
  float ni[2];
  #pragma unroll
  for (int nt = 0; nt < 2; nt++) ni[nt] = nrm[i0 + wcol * 32 + nt * 16 + c];

  // persistent GEMM1 af prefetch registers (ks=0 of current tile)
  bf16x8 af0c, af1c;
  {
    const ushort_t* ap = TbF + ((size_t)((chunk0 >> 4) + wj * 2) * 8) * 512 + lane * 8;
    af0c = *(const bf16x8*)ap;
    af1c = *(const bf16x8*)(ap + 4096);
  }

  __syncthreads();   // Gsm ready

  for (int jt = 0; jt < CHUNK; jt += TJ) {
    const int j0g = chunk0 + jt;
    ushort_t* Kbuf = Ksm[(jt >> 7) & 1];
    const ushort_t* afp = TbF + ((size_t)((j0g >> 4) + wj * 2) * 8) * 512 + lane * 8;

    // prefetch nrm[j] for this tile's epilogue (hidden under GEMM1)
    float4 njv[2];
    #pragma unroll
    for (int mt = 0; mt < 2; mt++)
      njv[mt] = *(const float4*)&nrm[j0g + wj * 32 + mt * 16 + q * 4];

    // ---- GEMM1: S^T[j32 x i32] per wave, K=256; af global (dbuf), bf from Gsm ----
    f32x4 acc1[2][2];
    #pragma unroll
    for (int m = 0; m < 2; m++)
      #pragma unroll
      for (int n = 0; n < 2; n++) acc1[m][n] = (f32x4)0.f;

    #pragma unroll
    for (int ks = 0; ks < 8; ks++) {
      bf16x8 afn0, afn1;
      if (ks < 7) {
        afn0 = *(const bf16x8*)(afp + (ks + 1) * 512);
        afn1 = *(const bf16x8*)(afp + 4096 + (ks + 1) * 512);
      }
      bf16x8 bf[2];
      #pragma unroll
      for (int nt = 0; nt < 2; nt++)
        bf[nt] = *(const bf16x8*)&Gsm[(ks >> 1) * 4096 + (wcol * 32 + nt * 16 + c) * 64 + ((((ks & 1) * 32) + q * 8) ^ swz)];
      #pragma unroll
      for (int nt = 0; nt < 2; nt++) {
        acc1[0][nt] = __builtin_amdgcn_mfma_f32_16x16x32_bf16(af0c, bf[nt], acc1[0][nt], 0, 0, 0);
        acc1[1][nt] = __builtin_amdgcn_mfma_f32_16x16x32_bf16(af1c, bf[nt], acc1[1][nt], 0, 0, 0);
      }
      if (ks < 7) { af0c = afn0; af1c = afn1; }
    }

    // ---- epilogue: kv = exp(-dist/20), rowsums, pack -> Kbuf ----
    #pragma unroll
    for (int mt = 0; mt < 2; mt++) {
      const int jl = wj * 32 + mt * 16 + q * 4;   // local j of reg 0
      const int jb = j0g + jl;                    // global j
      const float nj[4] = {njv[mt].x, njv[mt].y, njv[mt].z, njv[mt].w};
      #pragma unroll
      for (int nt = 0; nt < 2; nt++) {
        const int il = wcol * 32 + nt * 16 + c;
        const int ig = i0 + il;
        uint32_t pb[4];
        #pragma unroll
        for (int reg = 0; reg < 4; reg++) {
          float sq = fmaxf(ni[nt] + nj[reg] - 2.f * acc1[mt][nt][reg], 0.f);
          float dd = fast_sqrt(sq);
          float kv = fast_exp2(dd * -0.07213475204444817f);  // exp(-dd/20)
          if (gen && (jb + reg == ig)) kv = 0.f;
          rs[nt] += kv;
          union { float f; uint32_t u; } uu; uu.f = kv; pb[reg] = uu.u;
        }
        uint2 pk;  // truncating bf16 pack
        pk.x = __builtin_amdgcn_perm(pb[1], pb[0], 0x07060302u);
        pk.y = __builtin_amdgcn_perm(pb[3], pb[2], 0x07060302u);
        *(uint2*)&Kbuf[il * 128 + (jl ^ swz)] = pk;
      }
    }

    // pre-barrier prefetches: completed by the barrier's vmcnt(0) drain,
    // issued under the epilogue VALU work above.
    //  - this tile's a2 ks=0 pair (GEMM2 starts with operands ready)
    //  - next tile's af ks=0 pair (GEMM1 of tile jt+TJ starts ready)
    const ushort_t* a2p = TTF + ((size_t)(wd * 2) * jsteps + (j0g >> 5)) * 512 + lane * 8;
    bf16x8 a20 = *(const bf16x8*)a2p;
    bf16x8 a21 = *(const bf16x8*)(a2p + mstride);
    {
      const int jn = (jt + TJ < CHUNK) ? (j0g + TJ) : chunk0;
      const ushort_t* ap = TbF + ((size_t)((jn >> 4) + wj * 2) * 8) * 512 + lane * 8;
      af0c = *(const bf16x8*)ap;
      af1c = *(const bf16x8*)(ap + 4096);
    }

    __syncthreads();   // Kbuf ready (sole barrier; dbuf covers cross-tile reuse)

    // ---- GEMM2: O^T[d32 x i64] per wave, K=128; a2 global (dbuf), kf from Kbuf ----
    #pragma unroll
    for (int ks = 0; ks < 4; ks++) {
      bf16x8 a2n0, a2n1;
      if (ks < 3) {
        a2n0 = *(const bf16x8*)(a2p + (ks + 1) * 512);
        a2n1 = *(const bf16x8*)(a2p + mstride + (ks + 1) * 512);
      }
      bf16x8 kf[4];
      #pragma unroll
      for (int nt = 0; nt < 4; nt++)
        kf[nt] = *(const bf16x8*)&Kbuf[(nt * 16 + c) * 128 + ((ks * 32 + q * 8) ^ swz)];
      #pragma unroll
      for (int nt = 0; nt < 4; nt++) {
        accO[0][nt] = __builtin_amdgcn_mfma_f32_16x16x32_bf16(a20, kf[nt], accO[0][nt], 0, 0, 0);
        accO[1][nt] = __builtin_amdgcn_mfma_f32_16x16x32_bf16(a21, kf[nt], accO[1][nt], 0, 0, 0);
      }
      if (ks < 3) { a20 = a2n0; a21 = a2n1; }
    }
    // no barrier: next tile writes the other Ksm buffer
  }

  // rowsum partials -> sg/sp
  float* S = gen ? sg : sp;
  #pragma unroll
  for (int nt = 0; nt < 2; nt++) {
    float r = rs[nt];
    r += __shfl_xor(r, 16, 64);
    r += __shfl_xor(r, 32, 64);
    if (lane < 16) atomicAdd(&S[i0 + wcol * 32 + nt * 16 + lane], r);
  }
  // O^T partials -> Part[chunk][i][d] (f32x4, 16B aligned)
  float* Pdst = Part + (size_t)by * ((size_t)8192 * D_DIM);
  #pragma unroll
  for (int mt = 0; mt < 2; mt++)
    #pragma unroll
    for (int nt = 0; nt < 4; nt++) {
      const int d = wd * 32 + mt * 16 + q * 4;
      const int ig = i0 + nt * 16 + c;
      *(f32x4*)&Pdst[(size_t)ig * D_DIM + d] = accO[mt][nt];
    }
}

// ---------------- combine: out = sg*sum(pos parts) - sp*sum(gen parts) ----------------
__global__ __launch_bounds__(256) void
combine_kernel(float* __restrict__ out, const float* __restrict__ Part,
               const float* __restrict__ sg, const float* __restrict__ sp)
{
  const size_t idx = (size_t)blockIdx.x * 256 + threadIdx.x;   // f32x4 index
  const size_t qstride = (size_t)8192 * (D_DIM / 4);
  const int i = (int)(idx >> 6);
  const f32x4* p = (const f32x4*)Part;
  f32x4 g0 = p[idx], g1 = p[idx + qstride];
  f32x4 p0 = p[idx + 2 * qstride], p1 = p[idx + 3 * qstride];
  const float sgv = sg[i], spv = sp[i];
  f32x4 r;
  #pragma unroll
  for (int k = 0; k < 4; k++) r[k] = sgv * (p0[k] + p1[k]) - spv * (g0[k] + g1[k]);
  ((f32x4*)out)[idx] = r;
}

extern "C" void kernel_launch(void* const* d_in, const int* in_sizes, int n_in,
                              void* d_out, int out_size, void* d_ws, size_t ws_size,
                              hipStream_t stream)
{
  const float* G = (const float*)d_in[0];
  const float* P = (const float*)d_in[1];
  const int Bn = in_sizes[0] / D_DIM;   // 8192
  const int Xn = in_sizes[1] / D_DIM;   // 8192
  const int Ttot = Bn + Xn;             // 16384

  // workspace (~56.4 MiB)
  uint8_t* ws = (uint8_t*)d_ws;
  size_t off = 0;
  ushort_t* Tb  = (ushort_t*)(ws + off); off += (size_t)Ttot * D_DIM * 2;  // 8 MiB
  ushort_t* TbF = (ushort_t*)(ws + off); off += (size_t)Ttot * D_DIM * 2;  // 8 MiB
  ushort_t* TTF = (ushort_t*)(ws + off); off += (size_t)Ttot * D_DIM * 2;  // 8 MiB
  float* nrm = (float*)(ws + off); off += (size_t)Ttot * 4;
  float* sg  = (float*)(ws + off); off += (size_t)Bn * 4;
  float* sp  = (float*)(ws + off); off += (size_t)Bn * 4;
  off = (off + 255) & ~(size_t)255;
  float* Part = (float*)(ws + off); off += (size_t)4 * Bn * D_DIM * 4;     // 32 MiB
  if (ws_size < off) return;  // clean-fail signature if ws too small

  // zero nrm + sg + sp (contiguous)
  hipMemsetAsync(nrm, 0, ((size_t)Ttot + 2 * (size_t)Bn) * sizeof(float), stream);

  prep_AB<<<Ttot / 16, 256, 0, stream>>>(G, P, Tb, TbF, nrm, Bn);
  prep_fragT<<<dim3(Ttot / 64, D_DIM / 64), 256, 0, stream>>>(Tb, TTF, Ttot);
  fused_kernel<<<dim3(Bn / BI, Ttot / CHUNK), 512, 0, stream>>>(
      Tb, TbF, TTF, nrm, sg, sp, Part, Bn, Ttot);
  combine_kernel<<<(Bn * D_DIM / 4) / 256, 256, 0, stream>>>((float*)d_out, Part, sg, sp);
}